// Round 1
// baseline (2443.806 us; speedup 1.0000x reference)
//
#include <hip/hip_runtime.h>

#define N_NODES 500000
#define N_EDGES 8000000
#define CONSTRAINT_WEIGHT 0.1f
#define CORRECTION_FACTOR 0.1f

// Kernel 1: copy pos -> out (pos_new starts as pos), zero the loss accumulator.
__global__ void copy_init_kernel(const float4* __restrict__ pos4,
                                 float4* __restrict__ out4,
                                 int n4, double* __restrict__ ws_acc) {
    int i = blockIdx.x * blockDim.x + threadIdx.x;
    if (i == 0) *ws_acc = 0.0;
    int stride = gridDim.x * blockDim.x;
    for (int k = i; k < n4; k += stride)
        out4[k] = pos4[k];
}

// Kernel 2: per-edge gather/compute/scatter + loss reduction.
__global__ void edge_kernel(const float* __restrict__ pos,
                            const int* __restrict__ eidx,     // [2*E], row then col
                            const int* __restrict__ btype,    // [E]
                            const float* __restrict__ tl,     // [5]
                            const float* __restrict__ la,     // [5]
                            float* __restrict__ out_pos,      // [N*3]
                            double* __restrict__ ws_acc) {
    __shared__ float s_tgt[5];
    if (threadIdx.x < 5) s_tgt[threadIdx.x] = tl[threadIdx.x] + la[threadIdx.x];
    __syncthreads();

    float lsum = 0.0f;
    int stride = gridDim.x * blockDim.x;
    for (int e = blockIdx.x * blockDim.x + threadIdx.x; e < N_EDGES; e += stride) {
        int r = eidx[e];
        int c = eidx[N_EDGES + e];
        int bt = btype[e];
        bt = min(max(bt, 0), 4);
        float tgt = s_tgt[bt];

        float ax = pos[3 * r], ay = pos[3 * r + 1], az = pos[3 * r + 2];
        float bx = pos[3 * c], by = pos[3 * c + 1], bz = pos[3 * c + 2];
        float dx = ax - bx, dy = ay - by, dz = az - bz;

        float len = sqrtf(dx * dx + dy * dy + dz * dz);
        len = fmaxf(len, 1e-6f);
        lsum += fabsf(len - tgt);

        float ratio = tgt / len;
        ratio = fminf(fmaxf(ratio, 0.8f), 1.2f);
        float s = (ratio - 1.0f) * (CORRECTION_FACTOR * 0.5f);
        float hx = dx * s, hy = dy * s, hz = dz * s;

        atomicAdd(&out_pos[3 * r],     hx);
        atomicAdd(&out_pos[3 * r + 1], hy);
        atomicAdd(&out_pos[3 * r + 2], hz);
        atomicAdd(&out_pos[3 * c],    -hx);
        atomicAdd(&out_pos[3 * c + 1], -hy);
        atomicAdd(&out_pos[3 * c + 2], -hz);
    }

    // wave (64-lane) reduction
    for (int off = 32; off; off >>= 1)
        lsum += __shfl_down(lsum, off, 64);

    __shared__ float warp_sums[16];
    int wid = threadIdx.x >> 6;
    int lane = threadIdx.x & 63;
    if (lane == 0) warp_sums[wid] = lsum;
    __syncthreads();
    if (threadIdx.x == 0) {
        float bsum = 0.0f;
        int nw = blockDim.x >> 6;
        for (int w = 0; w < nw; ++w) bsum += warp_sums[w];
        atomicAdd(ws_acc, (double)bsum);
    }
}

// Kernel 3: finalize loss.
__global__ void finalize_kernel(const double* __restrict__ ws_acc,
                                float* __restrict__ out_loss) {
    *out_loss = (float)(*ws_acc / (double)N_EDGES * (double)CONSTRAINT_WEIGHT);
}

extern "C" void kernel_launch(void* const* d_in, const int* in_sizes, int n_in,
                              void* d_out, int out_size, void* d_ws, size_t ws_size,
                              hipStream_t stream) {
    const float* pos   = (const float*)d_in[0];
    const int*   eidx  = (const int*)d_in[1];
    const int*   btype = (const int*)d_in[2];
    const float* tl    = (const float*)d_in[3];
    const float* la    = (const float*)d_in[4];
    float*  out = (float*)d_out;
    double* ws  = (double*)d_ws;

    int n4 = (N_NODES * 3) / 4;  // 1,500,000 / 4 = 375,000
    copy_init_kernel<<<1024, 256, 0, stream>>>((const float4*)pos, (float4*)out, n4, ws);
    edge_kernel<<<4096, 256, 0, stream>>>(pos, eidx, btype, tl, la, out, ws);
    finalize_kernel<<<1, 1, 0, stream>>>(ws, out + N_NODES * 3);
}